// Round 4
// baseline (185.224 us; speedup 1.0000x reference)
//
#include <hip/hip_runtime.h>

// SymmetricContraction: out[n,c,i] = cubic polynomial in x[n,c,:] with
// species/channel-dependent coefficients (968 monomials, padded to 1024).
//   coef[s,t,c,0:4] = mult_t * sum_k u[t,k,i] w[s,k,c]
//   out[n,c,i]      = sum_t coef[idx_n,t,c,i] * x_a x_b x_j
// Pipeline (3 dispatches):
//   coef_setup : coef table (~21 MB ws), u staged in LDS cooperatively;
//                + species-bucketed atom order (one spare block); CT=8
//   contract   : DIRECT-LOAD polynomial eval — each lane streams its own
//                coef[t] float4 (coalesced, 16B/lane) with a fully unrolled
//                128-term loop; NO LDS, NO barriers. Inter-wave coef reuse
//                (4 waves x same tile) is served by L1. Deep ILP hides
//                L2/L3/HBM latency; waves fully decoupled.
//   reduce     : out = sum over 8 chunk partials
// ws requirement: ~29.4 MiB.
// R1 lesson: raw-barrier + counted-vmcnt + sched_barrier(0) pinning caused
//   scratch traffic (WRITE 34->119 MB) -> 2.2x regression.
// R2 lesson: TILE=16 hurt (46->57 us) — longer drain, same stall.
// R3 lesson: XCD-pinning cut FETCH 60->43 MB but dur 46->73 us (same-address
//   L2 contention). -> The LDS+barrier structure itself was the bottleneck:
//   staged bytes have no reuse beyond what L1 gives; this version removes it.

#define DD     16
#define NATOM  512
#define NCH    128
#define NSPEC  10
#define NT3    816
#define NT2    136
#define NT     968
#define NTP    1024  // 8 chunks x 128 terms
#define ATB    16    // atoms per eval block (same species)
#define APT    4     // atoms per thread
#define MAXB   42    // >= sum_s ceil(cnt_s/ATB)
#define CHUNKS 8
#define NTC    128   // terms per chunk
#define CHALF  2     // channel halves (64 ch per block)
#define CT     8     // terms per coef block (1290 blocks, ~5/CU)

#define WS_DESC  0
#define WS_ORDER 1024
#define WS_COEF  8192
#define COEF_BYTES (NSPEC * NTP * NCH * 16)       // 20,971,520
#define WS_PART  (WS_COEF + COEF_BYTES)           // partials: 8 x 1 MB

// ---------------- compile-time term table ----------------
// pack: a | b<<5 | j<<10 | kind<<15 | mult<<18
// slots in contract: 0..15 -> x[d], 16 -> 1.0f, 17 -> 0.0f
struct TermTable { unsigned v[NTP]; };
constexpr TermTable build_terms() {
  TermTable T{};
  int t = 0;
  for (int a = 0; a < DD; a++)
    for (int b = a; b < DD; b++)
      for (int j = b; j < DD; j++) {
        unsigned m = (a == b && b == j) ? 1u : ((a == b || b == j) ? 3u : 6u);
        T.v[t++] = (unsigned)(a | (b << 5) | (j << 10) | (3u << 15) | (m << 18));
      }
  for (int a = 0; a < DD; a++)
    for (int b = a; b < DD; b++) {
      unsigned m = (a == b) ? 1u : 2u;
      T.v[t++] = (unsigned)(a | (b << 5) | (16 << 10) | (2u << 15) | (m << 18));
    }
  for (int a = 0; a < DD; a++)
    T.v[t++] = (unsigned)(a | (16 << 5) | (16 << 10) | (1u << 15) | (1u << 18));
  while (t < NTP) T.v[t++] = (unsigned)(17 | (17 << 5) | (17 << 10));
  return T;
}
constexpr TermTable TERMS = build_terms();

// ---------------- setup: species bucketing ----------------
__device__ void do_setup(const int* __restrict__ index, int* __restrict__ desc,
                         int* __restrict__ order) {
  __shared__ int cnt[NSPEC], cursor[NSPEC], bbase[NSPEC + 1];
  const int tid = threadIdx.x;  // 0..127
  if (tid < NSPEC) { cnt[tid] = 0; cursor[tid] = 0; }
  __syncthreads();
  for (int i = tid; i < NATOM; i += 128) atomicAdd(&cnt[index[i]], 1);
  for (int i = tid; i < MAXB * ATB; i += 128) order[i] = -1;
  __syncthreads();
  if (tid == 0) {
    int base = 0;
    for (int s = 0; s < NSPEC; s++) { bbase[s] = base; base += (cnt[s] + ATB - 1) / ATB; }
    bbase[NSPEC] = base;
  }
  __syncthreads();
  for (int i = tid; i < NATOM; i += 128) {
    int s = index[i];
    int pos = atomicAdd(&cursor[s], 1);
    order[bbase[s] * ATB + pos] = i;
  }
  for (int i = tid; i < MAXB; i += 128) {
    int sp = -1;
    for (int s = 0; s < NSPEC; s++)
      if (i >= bbase[s] && i < bbase[s + 1]) sp = s;
    desc[i] = sp;
  }
}

// ---------------- coefficient build (+fused setup) ----------------
__global__ __launch_bounds__(128) void coef_setup_kernel(
    const float* __restrict__ u3_0, const float* __restrict__ w3_0,
    const float* __restrict__ u2_0, const float* __restrict__ w2_0,
    const float* __restrict__ u1_0, const float* __restrict__ w1_0,
    const float* __restrict__ u3_1, const float* __restrict__ w3_1,
    const float* __restrict__ u2_1, const float* __restrict__ w2_1,
    const float* __restrict__ u1_1, const float* __restrict__ w1_1,
    const int* __restrict__ index, int* __restrict__ desc,
    int* __restrict__ order, float* __restrict__ coef) {
  if (blockIdx.y == NTP / CT) {                // spare row: setup
    if (blockIdx.x == 0) do_setup(index, desc, order);
    return;
  }
  const int s = blockIdx.x;
  const int c = threadIdx.x;
  const int tbase = blockIdx.y * CT;

  __shared__ float us0[CT][23];
  __shared__ float us1[CT][99];

  // cooperative u staging (coalesced; addresses uniform per term, lane-split)
  for (int i = 0; i < CT; ++i) {
    const unsigned ev = TERMS.v[tbase + i];
    const int kind = (ev >> 15) & 7;
    const int a = ev & 31, b = (ev >> 5) & 31, j = (ev >> 10) & 31;
    if (kind == 3) {
      const int off = (a * DD + b) * DD + j;
      if (c < 23) us0[i][c] = u3_0[off * 23 + c];
      else if (c < 122) us1[i][c - 23] = u3_1[(size_t)off * 99 + (c - 23)];
    } else if (kind == 2) {
      const int off = a * DD + b;
      if (c < 4) us0[i][c] = u2_0[off * 4 + c];
      else if (c < 22) us1[i][c - 4] = u2_1[off * 18 + (c - 4)];
    } else if (kind == 1) {
      if (c < 1) us0[i][0] = u1_0[a];
      else if (c < 4) us1[i][c - 1] = u1_1[a * 3 + (c - 1)];
    }
  }
  __syncthreads();

  float r3_0[23], r3_1[33], r2_0[4], r2_1[6];
#pragma unroll
  for (int k = 0; k < 23; k++) r3_0[k] = w3_0[(s * 23 + k) * NCH + c];
#pragma unroll
  for (int k = 0; k < 33; k++) r3_1[k] = w3_1[(s * 33 + k) * NCH + c];
#pragma unroll
  for (int k = 0; k < 4; k++) r2_0[k] = w2_0[(s * 4 + k) * NCH + c];
#pragma unroll
  for (int k = 0; k < 6; k++) r2_1[k] = w2_1[(s * 6 + k) * NCH + c];
  const float r1_0 = w1_0[s * NCH + c];
  const float r1_1 = w1_1[s * NCH + c];

  for (int i = 0; i < CT; ++i) {
    const unsigned ev = TERMS.v[tbase + i];
    const int kind = (ev >> 15) & 7;
    const float fm = (float)((ev >> 18) & 7);
    float s0 = 0.f, s1 = 0.f, s2 = 0.f, s3 = 0.f;
    if (kind == 3) {
#pragma unroll
      for (int k = 0; k < 23; k++) s0 += us0[i][k] * r3_0[k];
#pragma unroll
      for (int k = 0; k < 33; k++) {
        const float w = r3_1[k];
        s1 += us1[i][k * 3 + 0] * w;
        s2 += us1[i][k * 3 + 1] * w;
        s3 += us1[i][k * 3 + 2] * w;
      }
    } else if (kind == 2) {
#pragma unroll
      for (int k = 0; k < 4; k++) s0 += us0[i][k] * r2_0[k];
#pragma unroll
      for (int k = 0; k < 6; k++) {
        const float w = r2_1[k];
        s1 += us1[i][k * 3 + 0] * w;
        s2 += us1[i][k * 3 + 1] * w;
        s3 += us1[i][k * 3 + 2] * w;
      }
    } else if (kind == 1) {
      s0 = us0[i][0] * r1_0;
      s1 = us1[i][0] * r1_1;
      s2 = us1[i][1] * r1_1;
      s3 = us1[i][2] * r1_1;
    }
    *(float4*)(coef + ((size_t)(s * NTP + tbase + i) * NCH + c) * 4) =
        float4{fm * s0, fm * s1, fm * s2, fm * s3};
  }
}

// ---------------- contract: direct-load polynomial eval ----------------
template <int CH>
__device__ __forceinline__ void eval_chunk(const float* __restrict__ lane_base,
                                           const float (&xr)[APT][18],
                                           float (&ac)[APT][4]) {
  constexpr int T0 = CH * NTC;
#pragma unroll
  for (int t = 0; t < NTC; ++t) {
    const unsigned ev = TERMS.v[T0 + t];       // compile-time const
    const int ea = ev & 31, eb = (ev >> 5) & 31, ej = (ev >> 10) & 31;
    // coalesced: lane stride 16B; independent loads -> deep ILP, no barriers
    const float4 cf = *(const float4*)(lane_base + (size_t)(T0 + t) * (NCH * 4));
#pragma unroll
    for (int k = 0; k < APT; ++k) {
      const float m = xr[k][ea] * xr[k][eb] * xr[k][ej];
      ac[k][0] += cf.x * m; ac[k][1] += cf.y * m;
      ac[k][2] += cf.z * m; ac[k][3] += cf.w * m;
    }
  }
}

__device__ __forceinline__ void load16(float (&xr)[18], const float* __restrict__ p) {
  const float4* q = (const float4*)p;
  const float4 v0 = q[0], v1 = q[1], v2 = q[2], v3 = q[3];
  xr[0] = v0.x; xr[1] = v0.y; xr[2] = v0.z; xr[3] = v0.w;
  xr[4] = v1.x; xr[5] = v1.y; xr[6] = v1.z; xr[7] = v1.w;
  xr[8] = v2.x; xr[9] = v2.y; xr[10] = v2.z; xr[11] = v2.w;
  xr[12] = v3.x; xr[13] = v3.y; xr[14] = v3.z; xr[15] = v3.w;
}

__global__ __launch_bounds__(256, 4) void contract_kernel(const float* __restrict__ x,
                                                          const int* __restrict__ desc,
                                                          const int* __restrict__ order,
                                                          const float* __restrict__ coef,
                                                          float* __restrict__ partial) {
  const int s = desc[blockIdx.x];
  if (s < 0) return;                           // uniform per block
  const int lane = threadIdx.x & 63;
  const int wave = threadIdx.x >> 6;           // == atom group 0..3
  const int c = blockIdx.z * 64 + lane;

  int n[APT];
#pragma unroll
  for (int k = 0; k < APT; k++) n[k] = order[blockIdx.x * ATB + wave * APT + k];

  float xr[APT][18];
#pragma unroll
  for (int k = 0; k < APT; k++) {
#pragma unroll
    for (int i = 0; i < DD; i++) xr[k][i] = 0.f;
    xr[k][16] = 1.f;
    xr[k][17] = 0.f;
  }
#pragma unroll
  for (int k = 0; k < APT; k++)
    if (n[k] >= 0) load16(xr[k], x + ((size_t)n[k] * NCH + c) * DD);

  float ac[APT][4];
#pragma unroll
  for (int k = 0; k < APT; k++) { ac[k][0] = 0.f; ac[k][1] = 0.f; ac[k][2] = 0.f; ac[k][3] = 0.f; }

  const float* lane_base = coef + ((size_t)s * NTP * NCH + (size_t)blockIdx.z * 64 + lane) * 4;

  switch (blockIdx.y) {
    case 0: eval_chunk<0>(lane_base, xr, ac); break;
    case 1: eval_chunk<1>(lane_base, xr, ac); break;
    case 2: eval_chunk<2>(lane_base, xr, ac); break;
    case 3: eval_chunk<3>(lane_base, xr, ac); break;
    case 4: eval_chunk<4>(lane_base, xr, ac); break;
    case 5: eval_chunk<5>(lane_base, xr, ac); break;
    case 6: eval_chunk<6>(lane_base, xr, ac); break;
    default: eval_chunk<7>(lane_base, xr, ac); break;
  }

  float* pb = partial + (size_t)blockIdx.y * (NATOM * NCH * 4);
#pragma unroll
  for (int k = 0; k < APT; k++)
    if (n[k] >= 0)
      *(float4*)(pb + ((size_t)n[k] * NCH + c) * 4) =
          float4{ac[k][0], ac[k][1], ac[k][2], ac[k][3]};
}

// ---------------- final reduction over chunks ----------------
__global__ __launch_bounds__(256) void reduce_kernel(const float4* __restrict__ partial,
                                                     float4* __restrict__ out) {
  const int i = blockIdx.x * 256 + threadIdx.x;  // 0 .. NATOM*NCH-1
  float4 s{0.f, 0.f, 0.f, 0.f};
#pragma unroll
  for (int ch = 0; ch < CHUNKS; ch++) {
    const float4 v = partial[(size_t)ch * (NATOM * NCH) + i];
    s.x += v.x; s.y += v.y; s.z += v.z; s.w += v.w;
  }
  out[i] = s;
}

extern "C" void kernel_launch(void* const* d_in, const int* in_sizes, int n_in,
                              void* d_out, int out_size, void* d_ws, size_t ws_size,
                              hipStream_t stream) {
  const float* x    = (const float*)d_in[0];
  const int* index  = (const int*)d_in[1];
  const float* u3_0 = (const float*)d_in[2];
  const float* w3_0 = (const float*)d_in[3];
  const float* u2_0 = (const float*)d_in[4];
  const float* w2_0 = (const float*)d_in[5];
  const float* u1_0 = (const float*)d_in[6];
  const float* w1_0 = (const float*)d_in[7];
  const float* u3_1 = (const float*)d_in[8];
  const float* w3_1 = (const float*)d_in[9];
  const float* u2_1 = (const float*)d_in[10];
  const float* w2_1 = (const float*)d_in[11];
  const float* u1_1 = (const float*)d_in[12];
  const float* w1_1 = (const float*)d_in[13];
  float* out = (float*)d_out;

  char* ws = (char*)d_ws;
  int* desc      = (int*)(ws + WS_DESC);
  int* order     = (int*)(ws + WS_ORDER);
  float* coef    = (float*)(ws + WS_COEF);
  float* partial = (float*)(ws + WS_PART);

  coef_setup_kernel<<<dim3(NSPEC, NTP / CT + 1), 128, 0, stream>>>(
      u3_0, w3_0, u2_0, w2_0, u1_0, w1_0,
      u3_1, w3_1, u2_1, w2_1, u1_1, w1_1, index, desc, order, coef);
  contract_kernel<<<dim3(MAXB, CHUNKS, CHALF), 256, 0, stream>>>(x, desc, order, coef, partial);
  reduce_kernel<<<(NATOM * NCH) / 256, 256, 0, stream>>>((const float4*)partial, (float4*)out);
}

// Round 5
// 134.590 us; speedup vs baseline: 1.3762x; 1.3762x over previous
//
#include <hip/hip_runtime.h>

// SymmetricContraction: out[n,c,i] = cubic polynomial in x[n,c,:] with
// species/channel-dependent coefficients (968 monomials, padded to 1024).
//   coef[s,t,c,0:4] = mult_t * sum_k u[t,k,i] w[s,k,c]
//   out[n,c,i]      = sum_t coef[idx_n,t,c,i] * x_a x_b x_j
// Pipeline (3 dispatches):
//   coef_setup : coef table (~21 MB ws), u staged in LDS cooperatively;
//                + species-bucketed atom order (one spare block); CT=8
//   contract   : m97-style LDS pipeline (R0 structure, proven 46 us) —
//                coef tiles streamed via global_load_lds (16B, async),
//                double-buffered, __syncthreads per tile. TLP DOUBLED:
//                APT=2 / ATB=8 -> ~1184 blocks (4.6/CU, 18.5 waves/CU)
//                so resident waves hide the per-tile vmcnt drain.
//   reduce     : out = sum over 8 chunk partials
// ws requirement: ~29.4 MiB.
// R1 lesson: raw-barrier + counted-vmcnt + sched_barrier(0) caused scratch
//   traffic (WRITE 34->119 MB) -> 2.2x regression. Keep __syncthreads.
// R2 lesson: TILE=16 hurt (46->57) — longer drain, same stall. CT=8 helped.
// R3 lesson: XCD-pinning cut FETCH 60->43 MB but dur 46->73 (L2 contention).
// R4 lesson: direct per-lane loads hurt (46->70): compiler held VGPR=64,
//   ~5 loads in flight. global_load_lds transport is right; TLP was the
//   untouched axis (2.6 waves/SIMD cannot hide the drain).

#define DD     16
#define NATOM  512
#define NCH    128
#define NSPEC  10
#define NT3    816
#define NT2    136
#define NT     968
#define NTP    1024  // 8 chunks x 128 terms
#define ATB    8     // atoms per eval block (same species)
#define APT    2     // atoms per thread
#define MAXB   74    // >= sum_s ceil(cnt_s/ATB) (worst case 72)
#define CHUNKS 8
#define NTC    128   // terms per chunk
#define TILE   8     // terms per LDS tile
#define NTILES (NTC / TILE)  // 16
#define TPW    (TILE / 4)    // terms staged per wave (2)
#define CHALF  2     // channel halves (64 ch per block)
#define CT     8     // terms per coef block (10x128 blocks, ~5/CU)

#define WS_DESC  0
#define WS_ORDER 1024
#define WS_COEF  8192
#define COEF_BYTES (NSPEC * NTP * NCH * 16)       // 20,971,520
#define WS_PART  (WS_COEF + COEF_BYTES)           // partials: 8 x 1 MB

// ---------------- compile-time term table ----------------
// pack: a | b<<5 | j<<10 | kind<<15 | mult<<18
// slots in contract: 0..15 -> x[d], 16 -> 1.0f, 17 -> 0.0f
struct TermTable { unsigned v[NTP]; };
constexpr TermTable build_terms() {
  TermTable T{};
  int t = 0;
  for (int a = 0; a < DD; a++)
    for (int b = a; b < DD; b++)
      for (int j = b; j < DD; j++) {
        unsigned m = (a == b && b == j) ? 1u : ((a == b || b == j) ? 3u : 6u);
        T.v[t++] = (unsigned)(a | (b << 5) | (j << 10) | (3u << 15) | (m << 18));
      }
  for (int a = 0; a < DD; a++)
    for (int b = a; b < DD; b++) {
      unsigned m = (a == b) ? 1u : 2u;
      T.v[t++] = (unsigned)(a | (b << 5) | (16 << 10) | (2u << 15) | (m << 18));
    }
  for (int a = 0; a < DD; a++)
    T.v[t++] = (unsigned)(a | (16 << 5) | (16 << 10) | (1u << 15) | (1u << 18));
  while (t < NTP) T.v[t++] = (unsigned)(17 | (17 << 5) | (17 << 10));
  return T;
}
constexpr TermTable TERMS = build_terms();

// ---------------- setup: species bucketing ----------------
__device__ void do_setup(const int* __restrict__ index, int* __restrict__ desc,
                         int* __restrict__ order) {
  __shared__ int cnt[NSPEC], cursor[NSPEC], bbase[NSPEC + 1];
  const int tid = threadIdx.x;  // 0..127
  if (tid < NSPEC) { cnt[tid] = 0; cursor[tid] = 0; }
  __syncthreads();
  for (int i = tid; i < NATOM; i += 128) atomicAdd(&cnt[index[i]], 1);
  for (int i = tid; i < MAXB * ATB; i += 128) order[i] = -1;
  __syncthreads();
  if (tid == 0) {
    int base = 0;
    for (int s = 0; s < NSPEC; s++) { bbase[s] = base; base += (cnt[s] + ATB - 1) / ATB; }
    bbase[NSPEC] = base;
  }
  __syncthreads();
  for (int i = tid; i < NATOM; i += 128) {
    int s = index[i];
    int pos = atomicAdd(&cursor[s], 1);
    order[bbase[s] * ATB + pos] = i;
  }
  for (int i = tid; i < MAXB; i += 128) {
    int sp = -1;
    for (int s = 0; s < NSPEC; s++)
      if (i >= bbase[s] && i < bbase[s + 1]) sp = s;
    desc[i] = sp;
  }
}

// ---------------- coefficient build (+fused setup) ----------------
__global__ __launch_bounds__(128) void coef_setup_kernel(
    const float* __restrict__ u3_0, const float* __restrict__ w3_0,
    const float* __restrict__ u2_0, const float* __restrict__ w2_0,
    const float* __restrict__ u1_0, const float* __restrict__ w1_0,
    const float* __restrict__ u3_1, const float* __restrict__ w3_1,
    const float* __restrict__ u2_1, const float* __restrict__ w2_1,
    const float* __restrict__ u1_1, const float* __restrict__ w1_1,
    const int* __restrict__ index, int* __restrict__ desc,
    int* __restrict__ order, float* __restrict__ coef) {
  if (blockIdx.y == NTP / CT) {                // spare row: setup
    if (blockIdx.x == 0) do_setup(index, desc, order);
    return;
  }
  const int s = blockIdx.x;
  const int c = threadIdx.x;
  const int tbase = blockIdx.y * CT;

  __shared__ float us0[CT][23];
  __shared__ float us1[CT][99];

  // cooperative u staging (coalesced; addresses uniform per term, lane-split)
  for (int i = 0; i < CT; ++i) {
    const unsigned ev = TERMS.v[tbase + i];
    const int kind = (ev >> 15) & 7;
    const int a = ev & 31, b = (ev >> 5) & 31, j = (ev >> 10) & 31;
    if (kind == 3) {
      const int off = (a * DD + b) * DD + j;
      if (c < 23) us0[i][c] = u3_0[off * 23 + c];
      else if (c < 122) us1[i][c - 23] = u3_1[(size_t)off * 99 + (c - 23)];
    } else if (kind == 2) {
      const int off = a * DD + b;
      if (c < 4) us0[i][c] = u2_0[off * 4 + c];
      else if (c < 22) us1[i][c - 4] = u2_1[off * 18 + (c - 4)];
    } else if (kind == 1) {
      if (c < 1) us0[i][0] = u1_0[a];
      else if (c < 4) us1[i][c - 1] = u1_1[a * 3 + (c - 1)];
    }
  }
  __syncthreads();

  float r3_0[23], r3_1[33], r2_0[4], r2_1[6];
#pragma unroll
  for (int k = 0; k < 23; k++) r3_0[k] = w3_0[(s * 23 + k) * NCH + c];
#pragma unroll
  for (int k = 0; k < 33; k++) r3_1[k] = w3_1[(s * 33 + k) * NCH + c];
#pragma unroll
  for (int k = 0; k < 4; k++) r2_0[k] = w2_0[(s * 4 + k) * NCH + c];
#pragma unroll
  for (int k = 0; k < 6; k++) r2_1[k] = w2_1[(s * 6 + k) * NCH + c];
  const float r1_0 = w1_0[s * NCH + c];
  const float r1_1 = w1_1[s * NCH + c];

  for (int i = 0; i < CT; ++i) {
    const unsigned ev = TERMS.v[tbase + i];
    const int kind = (ev >> 15) & 7;
    const float fm = (float)((ev >> 18) & 7);
    float s0 = 0.f, s1 = 0.f, s2 = 0.f, s3 = 0.f;
    if (kind == 3) {
#pragma unroll
      for (int k = 0; k < 23; k++) s0 += us0[i][k] * r3_0[k];
#pragma unroll
      for (int k = 0; k < 33; k++) {
        const float w = r3_1[k];
        s1 += us1[i][k * 3 + 0] * w;
        s2 += us1[i][k * 3 + 1] * w;
        s3 += us1[i][k * 3 + 2] * w;
      }
    } else if (kind == 2) {
#pragma unroll
      for (int k = 0; k < 4; k++) s0 += us0[i][k] * r2_0[k];
#pragma unroll
      for (int k = 0; k < 6; k++) {
        const float w = r2_1[k];
        s1 += us1[i][k * 3 + 0] * w;
        s2 += us1[i][k * 3 + 1] * w;
        s3 += us1[i][k * 3 + 2] * w;
      }
    } else if (kind == 1) {
      s0 = us0[i][0] * r1_0;
      s1 = us1[i][0] * r1_1;
      s2 = us1[i][1] * r1_1;
      s3 = us1[i][2] * r1_1;
    }
    *(float4*)(coef + ((size_t)(s * NTP + tbase + i) * NCH + c) * 4) =
        float4{fm * s0, fm * s1, fm * s2, fm * s3};
  }
}

// ---------------- contract: LDS-pipelined polynomial eval ----------------
__device__ __forceinline__ void stage_tile(const float* __restrict__ lane_base,
                                           int t0_tile, float* dst_base, int wave) {
#pragma unroll
  for (int r = 0; r < TPW; ++r) {
    const int term = wave * TPW + r;                // 4 waves x TPW terms
    const float* g = lane_base + (size_t)(t0_tile + term) * (NCH * 4);
    float* l = dst_base + term * 256;               // 64 lanes x 4 floats
    __builtin_amdgcn_global_load_lds(
        (const __attribute__((address_space(1))) unsigned int*)g,
        (__attribute__((address_space(3))) unsigned int*)l, 16, 0, 0);
  }
}

template <int CH>
__device__ __forceinline__ void eval_chunk(const float* __restrict__ lane_base,
                                           float (*lbuf)[TILE * 256],
                                           int wave, int lane,
                                           const float (&xr)[APT][18],
                                           float (&ac)[APT][4]) {
  constexpr int T0 = CH * NTC;
  stage_tile(lane_base, T0, &lbuf[0][0], wave);
#pragma unroll
  for (int tile = 0; tile < NTILES; ++tile) {
    __syncthreads();  // drains vmcnt -> lbuf[tile&1] ready; prev compute done
    if (tile + 1 < NTILES)
      stage_tile(lane_base, T0 + (tile + 1) * TILE, &lbuf[(tile + 1) & 1][0], wave);
    const float* lb = &lbuf[tile & 1][0];
#pragma unroll
    for (int i = 0; i < TILE; ++i) {
      const unsigned ev = TERMS.v[T0 + tile * TILE + i];  // compile-time const
      const int ea = ev & 31, eb = (ev >> 5) & 31, ej = (ev >> 10) & 31;
      const float4 cf = *(const float4*)(lb + (i * 64 + lane) * 4);
#pragma unroll
      for (int k = 0; k < APT; ++k) {
        const float m = xr[k][ea] * xr[k][eb] * xr[k][ej];
        ac[k][0] += cf.x * m; ac[k][1] += cf.y * m;
        ac[k][2] += cf.z * m; ac[k][3] += cf.w * m;
      }
    }
  }
}

__device__ __forceinline__ void load16(float (&xr)[18], const float* __restrict__ p) {
  const float4* q = (const float4*)p;
  const float4 v0 = q[0], v1 = q[1], v2 = q[2], v3 = q[3];
  xr[0] = v0.x; xr[1] = v0.y; xr[2] = v0.z; xr[3] = v0.w;
  xr[4] = v1.x; xr[5] = v1.y; xr[6] = v1.z; xr[7] = v1.w;
  xr[8] = v2.x; xr[9] = v2.y; xr[10] = v2.z; xr[11] = v2.w;
  xr[12] = v3.x; xr[13] = v3.y; xr[14] = v3.z; xr[15] = v3.w;
}

__global__ __launch_bounds__(256, 4) void contract_kernel(const float* __restrict__ x,
                                                          const int* __restrict__ desc,
                                                          const int* __restrict__ order,
                                                          const float* __restrict__ coef,
                                                          float* __restrict__ partial) {
  const int s = desc[blockIdx.x];
  if (s < 0) return;                           // uniform per block
  const int lane = threadIdx.x & 63;
  const int wave = threadIdx.x >> 6;           // == atom group 0..3
  const int c = blockIdx.z * 64 + lane;

  __shared__ float lbuf[2][TILE * 256];        // 2 x 8 KB

  int n[APT];
#pragma unroll
  for (int k = 0; k < APT; k++) n[k] = order[blockIdx.x * ATB + wave * APT + k];

  float xr[APT][18];
#pragma unroll
  for (int k = 0; k < APT; k++) {
#pragma unroll
    for (int i = 0; i < DD; i++) xr[k][i] = 0.f;
    xr[k][16] = 1.f;
    xr[k][17] = 0.f;
  }
#pragma unroll
  for (int k = 0; k < APT; k++)
    if (n[k] >= 0) load16(xr[k], x + ((size_t)n[k] * NCH + c) * DD);

  float ac[APT][4];
#pragma unroll
  for (int k = 0; k < APT; k++) { ac[k][0] = 0.f; ac[k][1] = 0.f; ac[k][2] = 0.f; ac[k][3] = 0.f; }

  const float* lane_base = coef + ((size_t)s * NTP * NCH + (size_t)blockIdx.z * 64 + lane) * 4;

  switch (blockIdx.y) {
    case 0: eval_chunk<0>(lane_base, lbuf, wave, lane, xr, ac); break;
    case 1: eval_chunk<1>(lane_base, lbuf, wave, lane, xr, ac); break;
    case 2: eval_chunk<2>(lane_base, lbuf, wave, lane, xr, ac); break;
    case 3: eval_chunk<3>(lane_base, lbuf, wave, lane, xr, ac); break;
    case 4: eval_chunk<4>(lane_base, lbuf, wave, lane, xr, ac); break;
    case 5: eval_chunk<5>(lane_base, lbuf, wave, lane, xr, ac); break;
    case 6: eval_chunk<6>(lane_base, lbuf, wave, lane, xr, ac); break;
    default: eval_chunk<7>(lane_base, lbuf, wave, lane, xr, ac); break;
  }

  float* pb = partial + (size_t)blockIdx.y * (NATOM * NCH * 4);
#pragma unroll
  for (int k = 0; k < APT; k++)
    if (n[k] >= 0)
      *(float4*)(pb + ((size_t)n[k] * NCH + c) * 4) =
          float4{ac[k][0], ac[k][1], ac[k][2], ac[k][3]};
}

// ---------------- final reduction over chunks ----------------
__global__ __launch_bounds__(256) void reduce_kernel(const float4* __restrict__ partial,
                                                     float4* __restrict__ out) {
  const int i = blockIdx.x * 256 + threadIdx.x;  // 0 .. NATOM*NCH-1
  float4 s{0.f, 0.f, 0.f, 0.f};
#pragma unroll
  for (int ch = 0; ch < CHUNKS; ch++) {
    const float4 v = partial[(size_t)ch * (NATOM * NCH) + i];
    s.x += v.x; s.y += v.y; s.z += v.z; s.w += v.w;
  }
  out[i] = s;
}

extern "C" void kernel_launch(void* const* d_in, const int* in_sizes, int n_in,
                              void* d_out, int out_size, void* d_ws, size_t ws_size,
                              hipStream_t stream) {
  const float* x    = (const float*)d_in[0];
  const int* index  = (const int*)d_in[1];
  const float* u3_0 = (const float*)d_in[2];
  const float* w3_0 = (const float*)d_in[3];
  const float* u2_0 = (const float*)d_in[4];
  const float* w2_0 = (const float*)d_in[5];
  const float* u1_0 = (const float*)d_in[6];
  const float* w1_0 = (const float*)d_in[7];
  const float* u3_1 = (const float*)d_in[8];
  const float* w3_1 = (const float*)d_in[9];
  const float* u2_1 = (const float*)d_in[10];
  const float* w2_1 = (const float*)d_in[11];
  const float* u1_1 = (const float*)d_in[12];
  const float* w1_1 = (const float*)d_in[13];
  float* out = (float*)d_out;

  char* ws = (char*)d_ws;
  int* desc      = (int*)(ws + WS_DESC);
  int* order     = (int*)(ws + WS_ORDER);
  float* coef    = (float*)(ws + WS_COEF);
  float* partial = (float*)(ws + WS_PART);

  coef_setup_kernel<<<dim3(NSPEC, NTP / CT + 1), 128, 0, stream>>>(
      u3_0, w3_0, u2_0, w2_0, u1_0, w1_0,
      u3_1, w3_1, u2_1, w2_1, u1_1, w1_1, index, desc, order, coef);
  contract_kernel<<<dim3(MAXB, CHUNKS, CHALF), 256, 0, stream>>>(x, desc, order, coef, partial);
  reduce_kernel<<<(NATOM * NCH) / 256, 256, 0, stream>>>((const float4*)partial, (float4*)out);
}

// Round 6
// 127.834 us; speedup vs baseline: 1.4489x; 1.0529x over previous
//
#include <hip/hip_runtime.h>
#include <hip/hip_fp16.h>

// SymmetricContraction: out[n,c,i] = cubic polynomial in x[n,c,:] with
// species/channel-dependent coefficients (968 monomials, padded to 1024).
//   coef[s,t,c,0:4] = mult_t * sum_k u[t,k,i] w[s,k,c]   (stored FP16)
//   out[n,c,i]      = sum_t coef[idx_n,t,c,i] * x_a x_b x_j   (math FP32)
// Pipeline (3 dispatches):
//   coef_setup : coef table (~10.5 MB ws, fp16, layout [s][half][t][c'][i]),
//                u staged in LDS cooperatively; + species-bucketed atom
//                order (one spare block); CT=8
//   contract   : m97-style LDS pipeline — fp16 coef tiles streamed via
//                global_load_lds (16B, async; 1 load/wave covers 2 terms),
//                double-buffered, __syncthreads per tile; fp32 accumulate.
//                TLP: APT=2 / ATB=8 -> ~1184 blocks (4.6/CU, 18.5 waves/CU)
//   reduce     : out = sum over 8 chunk partials (fp32)
// ws requirement: ~18.9 MiB.
// R1: raw-barrier + counted-vmcnt + sched_barrier caused scratch traffic
//     (WRITE 34->119 MB) -> 2.2x regression. Keep __syncthreads cadence.
// R2: TILE=16 hurt (46->57) — longer drain, same stall. CT=8 helped (~7us).
// R3: XCD-pinning cut FETCH 60->43 MB but dur 46->73 (L2 contention).
// R4: direct per-lane loads hurt (46->70): VGPR=64 capped ILP at ~5 loads.
// R5 WIN: ATB 16->8 / APT 4->2 doubled TLP; contract ~46->~30, total 155->135.
//     -> latency-hiding comes from resident waves, not per-block structure.
// R6 (this): fp16 coef halves the dominant stream of both custom kernels;
//     absmax tolerance 0.5 >> expected ~0.02 rounding accumulation.

#define DD     16
#define NATOM  512
#define NCH    128
#define NSPEC  10
#define NTP    1024  // 8 chunks x 128 terms
#define ATB    8     // atoms per eval block (same species)
#define APT    2     // atoms per thread
#define MAXB   74    // >= sum_s ceil(cnt_s/ATB) (worst case 72)
#define CHUNKS 8
#define NTC    128   // terms per chunk
#define TILE   8     // terms per LDS tile
#define NTILES (NTC / TILE)  // 16
#define CHALF  2     // channel halves (64 ch per block)
#define CT     8     // terms per coef block (10x128 blocks, ~5/CU)

#define WS_DESC  0
#define WS_ORDER 1024
#define WS_COEF  8192
// fp16 coef: [s][half][t][c' (64)][i (4)] halves -> 8 B per (s,h,t,c')
#define COEF_BYTES (NSPEC * 2 * NTP * 64 * 4 * 2)  // 10,485,760
#define WS_PART  (WS_COEF + COEF_BYTES)            // partials: 8 x 1 MB

// ---------------- compile-time term table ----------------
// pack: a | b<<5 | j<<10 | kind<<15 | mult<<18
// slots in contract: 0..15 -> x[d], 16 -> 1.0f, 17 -> 0.0f
struct TermTable { unsigned v[NTP]; };
constexpr TermTable build_terms() {
  TermTable T{};
  int t = 0;
  for (int a = 0; a < DD; a++)
    for (int b = a; b < DD; b++)
      for (int j = b; j < DD; j++) {
        unsigned m = (a == b && b == j) ? 1u : ((a == b || b == j) ? 3u : 6u);
        T.v[t++] = (unsigned)(a | (b << 5) | (j << 10) | (3u << 15) | (m << 18));
      }
  for (int a = 0; a < DD; a++)
    for (int b = a; b < DD; b++) {
      unsigned m = (a == b) ? 1u : 2u;
      T.v[t++] = (unsigned)(a | (b << 5) | (16 << 10) | (2u << 15) | (m << 18));
    }
  for (int a = 0; a < DD; a++)
    T.v[t++] = (unsigned)(a | (16 << 5) | (16 << 10) | (1u << 15) | (1u << 18));
  while (t < NTP) T.v[t++] = (unsigned)(17 | (17 << 5) | (17 << 10));
  return T;
}
constexpr TermTable TERMS = build_terms();

// ---------------- setup: species bucketing ----------------
__device__ void do_setup(const int* __restrict__ index, int* __restrict__ desc,
                         int* __restrict__ order) {
  __shared__ int cnt[NSPEC], cursor[NSPEC], bbase[NSPEC + 1];
  const int tid = threadIdx.x;  // 0..127
  if (tid < NSPEC) { cnt[tid] = 0; cursor[tid] = 0; }
  __syncthreads();
  for (int i = tid; i < NATOM; i += 128) atomicAdd(&cnt[index[i]], 1);
  for (int i = tid; i < MAXB * ATB; i += 128) order[i] = -1;
  __syncthreads();
  if (tid == 0) {
    int base = 0;
    for (int s = 0; s < NSPEC; s++) { bbase[s] = base; base += (cnt[s] + ATB - 1) / ATB; }
    bbase[NSPEC] = base;
  }
  __syncthreads();
  for (int i = tid; i < NATOM; i += 128) {
    int s = index[i];
    int pos = atomicAdd(&cursor[s], 1);
    order[bbase[s] * ATB + pos] = i;
  }
  for (int i = tid; i < MAXB; i += 128) {
    int sp = -1;
    for (int s = 0; s < NSPEC; s++)
      if (i >= bbase[s] && i < bbase[s + 1]) sp = s;
    desc[i] = sp;
  }
}

// ---------------- coefficient build (+fused setup) ----------------
__global__ __launch_bounds__(128) void coef_setup_kernel(
    const float* __restrict__ u3_0, const float* __restrict__ w3_0,
    const float* __restrict__ u2_0, const float* __restrict__ w2_0,
    const float* __restrict__ u1_0, const float* __restrict__ w1_0,
    const float* __restrict__ u3_1, const float* __restrict__ w3_1,
    const float* __restrict__ u2_1, const float* __restrict__ w2_1,
    const float* __restrict__ u1_1, const float* __restrict__ w1_1,
    const int* __restrict__ index, int* __restrict__ desc,
    int* __restrict__ order, __half* __restrict__ coefh) {
  if (blockIdx.y == NTP / CT) {                // spare row: setup
    if (blockIdx.x == 0) do_setup(index, desc, order);
    return;
  }
  const int s = blockIdx.x;
  const int c = threadIdx.x;
  const int tbase = blockIdx.y * CT;

  __shared__ float us0[CT][23];
  __shared__ float us1[CT][99];

  // cooperative u staging (coalesced; addresses uniform per term, lane-split)
  for (int i = 0; i < CT; ++i) {
    const unsigned ev = TERMS.v[tbase + i];
    const int kind = (ev >> 15) & 7;
    const int a = ev & 31, b = (ev >> 5) & 31, j = (ev >> 10) & 31;
    if (kind == 3) {
      const int off = (a * DD + b) * DD + j;
      if (c < 23) us0[i][c] = u3_0[off * 23 + c];
      else if (c < 122) us1[i][c - 23] = u3_1[(size_t)off * 99 + (c - 23)];
    } else if (kind == 2) {
      const int off = a * DD + b;
      if (c < 4) us0[i][c] = u2_0[off * 4 + c];
      else if (c < 22) us1[i][c - 4] = u2_1[off * 18 + (c - 4)];
    } else if (kind == 1) {
      if (c < 1) us0[i][0] = u1_0[a];
      else if (c < 4) us1[i][c - 1] = u1_1[a * 3 + (c - 1)];
    }
  }
  __syncthreads();

  float r3_0[23], r3_1[33], r2_0[4], r2_1[6];
#pragma unroll
  for (int k = 0; k < 23; k++) r3_0[k] = w3_0[(s * 23 + k) * NCH + c];
#pragma unroll
  for (int k = 0; k < 33; k++) r3_1[k] = w3_1[(s * 33 + k) * NCH + c];
#pragma unroll
  for (int k = 0; k < 4; k++) r2_0[k] = w2_0[(s * 4 + k) * NCH + c];
#pragma unroll
  for (int k = 0; k < 6; k++) r2_1[k] = w2_1[(s * 6 + k) * NCH + c];
  const float r1_0 = w1_0[s * NCH + c];
  const float r1_1 = w1_1[s * NCH + c];

  for (int i = 0; i < CT; ++i) {
    const unsigned ev = TERMS.v[tbase + i];
    const int kind = (ev >> 15) & 7;
    const float fm = (float)((ev >> 18) & 7);
    float s0 = 0.f, s1 = 0.f, s2 = 0.f, s3 = 0.f;
    if (kind == 3) {
#pragma unroll
      for (int k = 0; k < 23; k++) s0 += us0[i][k] * r3_0[k];
#pragma unroll
      for (int k = 0; k < 33; k++) {
        const float w = r3_1[k];
        s1 += us1[i][k * 3 + 0] * w;
        s2 += us1[i][k * 3 + 1] * w;
        s3 += us1[i][k * 3 + 2] * w;
      }
    } else if (kind == 2) {
#pragma unroll
      for (int k = 0; k < 4; k++) s0 += us0[i][k] * r2_0[k];
#pragma unroll
      for (int k = 0; k < 6; k++) {
        const float w = r2_1[k];
        s1 += us1[i][k * 3 + 0] * w;
        s2 += us1[i][k * 3 + 1] * w;
        s3 += us1[i][k * 3 + 2] * w;
      }
    } else if (kind == 1) {
      s0 = us0[i][0] * r1_0;
      s1 = us1[i][0] * r1_1;
      s2 = us1[i][1] * r1_1;
      s3 = us1[i][2] * r1_1;
    }
    // pack 4 halves -> 8 B; layout [s][h][t][c'] with h=c>>6, c'=c&63
    union { __half2 h2[2]; uint2 u; } pk;
    pk.h2[0] = __floats2half2_rn(fm * s0, fm * s1);
    pk.h2[1] = __floats2half2_rn(fm * s2, fm * s3);
    const size_t off =
        (((size_t)(s * 2 + (c >> 6)) * NTP + (tbase + i)) * 64 + (c & 63));
    *(uint2*)((char*)coefh + off * 8) = pk.u;
  }
}

// ---------------- contract: LDS-pipelined polynomial eval ----------------
// One 16B/lane global_load_lds per wave covers 2 terms (1024 B contiguous):
// term-half row = 64 c' x 8 B = 512 B in the [s][h][t][c'] layout.
__device__ __forceinline__ void stage_tile(const unsigned* __restrict__ gbase,
                                           int t0_tile, float* dst_base,
                                           int wave, int lane) {
  const unsigned* g = gbase + (size_t)(t0_tile + 2 * wave) * 128 + lane * 4;
  __builtin_amdgcn_global_load_lds(
      (const __attribute__((address_space(1))) unsigned int*)g,
      (__attribute__((address_space(3))) unsigned int*)(dst_base + wave * 256),
      16, 0, 0);
}

template <int CH>
__device__ __forceinline__ void eval_chunk(const unsigned* __restrict__ gbase,
                                           float (*lbuf)[TILE * 128],
                                           int wave, int lane,
                                           const float (&xr)[APT][18],
                                           float (&ac)[APT][4]) {
  constexpr int T0 = CH * NTC;
  stage_tile(gbase, T0, &lbuf[0][0], wave, lane);
#pragma unroll
  for (int tile = 0; tile < NTILES; ++tile) {
    __syncthreads();  // drains vmcnt -> lbuf[tile&1] ready; prev compute done
    if (tile + 1 < NTILES)
      stage_tile(gbase, T0 + (tile + 1) * TILE, &lbuf[(tile + 1) & 1][0], wave, lane);
    const float* lb = &lbuf[tile & 1][0];
#pragma unroll
    for (int i = 0; i < TILE; ++i) {
      const unsigned ev = TERMS.v[T0 + tile * TILE + i];  // compile-time const
      const int ea = ev & 31, eb = (ev >> 5) & 31, ej = (ev >> 10) & 31;
      // 8 B/lane: 4 halves for this (term, c'); 2-way bank alias = free
      const uint2 raw = *(const uint2*)(lb + i * 128 + lane * 2);
      const float2 f01 = __half22float2(*reinterpret_cast<const __half2*>(&raw.x));
      const float2 f23 = __half22float2(*reinterpret_cast<const __half2*>(&raw.y));
#pragma unroll
      for (int k = 0; k < APT; ++k) {
        const float m = xr[k][ea] * xr[k][eb] * xr[k][ej];
        ac[k][0] += f01.x * m; ac[k][1] += f01.y * m;
        ac[k][2] += f23.x * m; ac[k][3] += f23.y * m;
      }
    }
  }
}

__device__ __forceinline__ void load16(float (&xr)[18], const float* __restrict__ p) {
  const float4* q = (const float4*)p;
  const float4 v0 = q[0], v1 = q[1], v2 = q[2], v3 = q[3];
  xr[0] = v0.x; xr[1] = v0.y; xr[2] = v0.z; xr[3] = v0.w;
  xr[4] = v1.x; xr[5] = v1.y; xr[6] = v1.z; xr[7] = v1.w;
  xr[8] = v2.x; xr[9] = v2.y; xr[10] = v2.z; xr[11] = v2.w;
  xr[12] = v3.x; xr[13] = v3.y; xr[14] = v3.z; xr[15] = v3.w;
}

__global__ __launch_bounds__(256, 4) void contract_kernel(const float* __restrict__ x,
                                                          const int* __restrict__ desc,
                                                          const int* __restrict__ order,
                                                          const __half* __restrict__ coefh,
                                                          float* __restrict__ partial) {
  const int s = desc[blockIdx.x];
  if (s < 0) return;                           // uniform per block
  const int lane = threadIdx.x & 63;
  const int wave = threadIdx.x >> 6;           // == atom group 0..3
  const int half = blockIdx.z;
  const int c = half * 64 + lane;

  __shared__ float lbuf[2][TILE * 128];        // 2 x 4 KB (fp16 coef)

  int n[APT];
#pragma unroll
  for (int k = 0; k < APT; k++) n[k] = order[blockIdx.x * ATB + wave * APT + k];

  float xr[APT][18];
#pragma unroll
  for (int k = 0; k < APT; k++) {
#pragma unroll
    for (int i = 0; i < DD; i++) xr[k][i] = 0.f;
    xr[k][16] = 1.f;
    xr[k][17] = 0.f;
  }
#pragma unroll
  for (int k = 0; k < APT; k++)
    if (n[k] >= 0) load16(xr[k], x + ((size_t)n[k] * NCH + c) * DD);

  float ac[APT][4];
#pragma unroll
  for (int k = 0; k < APT; k++) { ac[k][0] = 0.f; ac[k][1] = 0.f; ac[k][2] = 0.f; ac[k][3] = 0.f; }

  // [s][half] chunk base, dword units (term stride = 512 B = 128 dwords)
  const unsigned* gbase =
      (const unsigned*)coefh + (size_t)(s * 2 + half) * NTP * 128;

  switch (blockIdx.y) {
    case 0: eval_chunk<0>(gbase, lbuf, wave, lane, xr, ac); break;
    case 1: eval_chunk<1>(gbase, lbuf, wave, lane, xr, ac); break;
    case 2: eval_chunk<2>(gbase, lbuf, wave, lane, xr, ac); break;
    case 3: eval_chunk<3>(gbase, lbuf, wave, lane, xr, ac); break;
    case 4: eval_chunk<4>(gbase, lbuf, wave, lane, xr, ac); break;
    case 5: eval_chunk<5>(gbase, lbuf, wave, lane, xr, ac); break;
    case 6: eval_chunk<6>(gbase, lbuf, wave, lane, xr, ac); break;
    default: eval_chunk<7>(gbase, lbuf, wave, lane, xr, ac); break;
  }

  float* pb = partial + (size_t)blockIdx.y * (NATOM * NCH * 4);
#pragma unroll
  for (int k = 0; k < APT; k++)
    if (n[k] >= 0)
      *(float4*)(pb + ((size_t)n[k] * NCH + c) * 4) =
          float4{ac[k][0], ac[k][1], ac[k][2], ac[k][3]};
}

// ---------------- final reduction over chunks ----------------
__global__ __launch_bounds__(256) void reduce_kernel(const float4* __restrict__ partial,
                                                     float4* __restrict__ out) {
  const int i = blockIdx.x * 256 + threadIdx.x;  // 0 .. NATOM*NCH-1
  float4 s{0.f, 0.f, 0.f, 0.f};
#pragma unroll
  for (int ch = 0; ch < CHUNKS; ch++) {
    const float4 v = partial[(size_t)ch * (NATOM * NCH) + i];
    s.x += v.x; s.y += v.y; s.z += v.z; s.w += v.w;
  }
  out[i] = s;
}

extern "C" void kernel_launch(void* const* d_in, const int* in_sizes, int n_in,
                              void* d_out, int out_size, void* d_ws, size_t ws_size,
                              hipStream_t stream) {
  const float* x    = (const float*)d_in[0];
  const int* index  = (const int*)d_in[1];
  const float* u3_0 = (const float*)d_in[2];
  const float* w3_0 = (const float*)d_in[3];
  const float* u2_0 = (const float*)d_in[4];
  const float* w2_0 = (const float*)d_in[5];
  const float* u1_0 = (const float*)d_in[6];
  const float* w1_0 = (const float*)d_in[7];
  const float* u3_1 = (const float*)d_in[8];
  const float* w3_1 = (const float*)d_in[9];
  const float* u2_1 = (const float*)d_in[10];
  const float* w2_1 = (const float*)d_in[11];
  const float* u1_1 = (const float*)d_in[12];
  const float* w1_1 = (const float*)d_in[13];
  float* out = (float*)d_out;

  char* ws = (char*)d_ws;
  int* desc      = (int*)(ws + WS_DESC);
  int* order     = (int*)(ws + WS_ORDER);
  __half* coefh  = (__half*)(ws + WS_COEF);
  float* partial = (float*)(ws + WS_PART);

  coef_setup_kernel<<<dim3(NSPEC, NTP / CT + 1), 128, 0, stream>>>(
      u3_0, w3_0, u2_0, w2_0, u1_0, w1_0,
      u3_1, w3_1, u2_1, w2_1, u1_1, w1_1, index, desc, order, coefh);
  contract_kernel<<<dim3(MAXB, CHUNKS, CHALF), 256, 0, stream>>>(x, desc, order, coefh, partial);
  reduce_kernel<<<(NATOM * NCH) / 256, 256, 0, stream>>>((const float4*)partial, (float4*)out);
}